// Round 10
// baseline (94.077 us; speedup 1.0000x reference)
//
#include <hip/hip_runtime.h>
#include <hip/hip_bf16.h>

typedef __bf16 bf16_t;
typedef bf16_t bf16x4 __attribute__((ext_vector_type(4)));
typedef bf16_t bf16x8 __attribute__((ext_vector_type(8)));
typedef float f32x4 __attribute__((ext_vector_type(4)));
typedef __attribute__((address_space(1))) const unsigned int gu32_t;
typedef __attribute__((address_space(3))) unsigned int lu32_t;

#define MFMA(a, b, c) __builtin_amdgcn_mfma_f32_16x16x32_bf16(a, b, c, 0, 0, 0)

constexpr int B = 8, S = 2048, C = 1024, D = 128;
constexpr float C2 = 0.12751744f; // log2(e)/sqrt(128)

// Frag-major: frag(blk16, kk) = 1KB block; lane = ((k>>3)&3)*16 + (dim&15),
// 8 contiguous k per lane. Serves both A- and B-operands of mfma_16x16x32.

// ---------------- K0: W[c][n] -> Wf frag-major ----------------------------
__global__ __launch_bounds__(256) void k_wt(const float* Wq, const float* Wk, const float* Wv, bf16_t* Wf) {
    int ct = blockIdx.x, w = blockIdx.y; // ct 0..63, w 0..2
    const float* src = (w == 0) ? Wq : ((w == 1) ? Wk : Wv);
    __shared__ bf16_t tile[16][132];
    int t = threadIdx.x;
    int cr = t >> 4, dq = t & 15;
    const float* p = src + (size_t)(ct * 16 + cr) * D + dq * 8;
    f32x4 v0 = *(const f32x4*)p;
    f32x4 v1 = *(const f32x4*)(p + 4);
#pragma unroll
    for (int q = 0; q < 4; ++q) { tile[cr][dq * 8 + q] = (bf16_t)v0[q]; tile[cr][dq * 8 + 4 + q] = (bf16_t)v1[q]; }
    __syncthreads();
    int n = t >> 1, g = t & 1;
    bf16x8 o;
#pragma unroll
    for (int cc = 0; cc < 8; ++cc) o[cc] = tile[g * 8 + cc][n];
    int c8 = ct * 2 + g;
    int nblk = w * 8 + (n >> 4);
    size_t a = ((size_t)(nblk * 32 + (c8 >> 2)) * 64 + (c8 & 3) * 16 + (n & 15)) * 8;
    *(bf16x8*)(Wf + a) = o;
}

// ---------------- K1: fused QKV projection, 256 blocks x 64 rows ----------
// 2 K-chunks of 512c staged frag-major in LDS (64 KiB, 3 barriers total);
// per wave per kk-step: 3 W-frag L2 loads feed 12 MFMA (acc[4][3]).
// Also zeroes Out (k_out atomicAdds later).
__global__ __launch_bounds__(512, 4) void k_qkv(const float* X, const bf16_t* Wf,
                                                bf16_t* Qf, bf16_t* Kf, float* Vf,
                                                float* Out) {
    __shared__ __align__(16) bf16_t xfr[64 * 512]; // 64 frags x 1KB = 64 KiB
    int mt = blockIdx.x; // 0..255
    int t = threadIdx.x;
    int lane = t & 63, wid = t >> 6;
    int lr = lane & 15, lg = lane >> 4;
    int rw = mt * 64;

    { // zero Out: 256 blocks * 512 t * 4 f32x4 = 8.4 MB
        f32x4* O4 = (f32x4*)Out;
        f32x4 z = {};
        int u = mt * 512 + t;
        O4[u] = z; O4[u + 131072] = z; O4[u + 262144] = z; O4[u + 393216] = z;
    }

    auto stage = [&](int h) {
        f32x4 xa[8], xb[8];
#pragma unroll
        for (int p = 0; p < 8; ++p) {
            int fi = p * 8 + wid;          // rb = fi>>4 (0..3), kc = fi&15
            int m = rw + (fi >> 4) * 16 + lr;
            int c = h * 512 + (fi & 15) * 32 + lg * 8;
            const float* px = X + (size_t)m * C + c;
            xa[p] = *(const f32x4*)px;
            xb[p] = *(const f32x4*)(px + 4);
        }
#pragma unroll
        for (int p = 0; p < 8; ++p) {
            bf16x8 o;
#pragma unroll
            for (int q = 0; q < 4; ++q) { o[q] = (bf16_t)xa[p][q]; o[4 + q] = (bf16_t)xb[p][q]; }
            *(bf16x8*)&xfr[(size_t)(p * 8 + wid) * 512 + lane * 8] = o;
        }
    };

    f32x4 acc[4][3] = {};
    const bf16_t* wbase = Wf + (size_t)(wid * 3) * 32 * 512 + lane * 8;

    stage(0);
    __syncthreads();
#pragma unroll
    for (int h = 0; h < 2; ++h) {
        if (h) { __syncthreads(); stage(1); __syncthreads(); }
#pragma unroll 4
        for (int kk = 0; kk < 16; ++kk) {
            int kkg = h * 16 + kk;
            bf16x8 w[3];
#pragma unroll
            for (int nf = 0; nf < 3; ++nf)
                w[nf] = *(const bf16x8*)(wbase + (size_t)(nf * 32 + kkg) * 512);
#pragma unroll
            for (int rF = 0; rF < 4; ++rF) {
                bf16x8 a = *(const bf16x8*)&xfr[(size_t)(rF * 16 + kk) * 512 + lane * 8];
                acc[rF][0] = MFMA(a, w[0], acc[rF][0]);
                acc[rF][1] = MFMA(a, w[1], acc[rF][1]);
                acc[rF][2] = MFMA(a, w[2], acc[rF][2]);
            }
        }
    }
    // epilogue: scatter to frag-major Qf/Kf (bf16) or row-major Vf (fp32)
#pragma unroll
    for (int rF = 0; rF < 4; ++rF)
#pragma unroll
        for (int nf = 0; nf < 3; ++nf) {
            int n = wid * 48 + nf * 16 + lr;
            int sel = (wid * 48 + nf * 16) >> 7; // wave-uniform
            int nn = n & 127;
#pragma unroll
            for (int r = 0; r < 4; ++r) {
                int m = rw + rF * 16 + lg * 4 + r;
                float v = acc[rF][nf][r];
                if (sel == 2) {
                    Vf[(size_t)m * D + nn] = v;
                } else {
                    bf16_t* dst = (sel == 0) ? Qf : Kf;
                    size_t a = ((size_t)((m >> 4) * 4 + (nn >> 5)) * 64 + ((nn >> 3) & 3) * 16 + (m & 15)) * 8 + (nn & 7);
                    dst[a] = (bf16_t)v;
                }
            }
        }
}

// ---------------- K2: column sums l[j] (32 j/block), barrier-free sweep ----
__global__ __launch_bounds__(512, 4) void k_sum(const bf16_t* Qf, const bf16_t* Kf,
                                                const float* Vf, bf16_t* Vt2) {
    int l = blockIdx.x;          // 512 blocks
    int b = l & 7, jt = l >> 3;  // b pinned to XCD; jt 0..63
    int j0 = jt * 32;
    int t = threadIdx.x;
    int lane = t & 63, wid = t >> 6;
    __shared__ __align__(16) bf16_t vtile[128 * 40]; // 10 KiB
    __shared__ float lsum[256];
    __shared__ float linv[32];

    bf16x8 kf[2][4];
    int jblkg = (b * S + j0) >> 4;
#pragma unroll
    for (int jF = 0; jF < 2; ++jF)
#pragma unroll
        for (int kk = 0; kk < 4; ++kk)
            kf[jF][kk] = *(const bf16x8*)(Kf + ((size_t)((jblkg + jF) * 4 + kk) * 64 + lane) * 8);

    float ls0 = 0.f, ls1 = 0.f;
#pragma unroll 4
    for (int tt = 0; tt < 16; ++tt) {
        int iblk = (b * S + wid * 256 + tt * 16) >> 4;
        bf16x8 qa[4];
#pragma unroll
        for (int kk = 0; kk < 4; ++kk)
            qa[kk] = *(const bf16x8*)(Qf + ((size_t)(iblk * 4 + kk) * 64 + lane) * 8);
        f32x4 s0 = {}, s1 = {};
#pragma unroll
        for (int kk = 0; kk < 4; ++kk) {
            s0 = MFMA(qa[kk], kf[0][kk], s0);
            s1 = MFMA(qa[kk], kf[1][kk], s1);
        }
#pragma unroll
        for (int r = 0; r < 4; ++r) { ls0 += exp2f(s0[r] * C2); ls1 += exp2f(s1[r] * C2); }
    }
    {
        float v0 = ls0 + __shfl_xor(ls0, 16); v0 += __shfl_xor(v0, 32);
        float v1 = ls1 + __shfl_xor(ls1, 16); v1 += __shfl_xor(v1, 32);
        if (lane < 16) { lsum[wid * 32 + lane] = v0; lsum[wid * 32 + 16 + lane] = v1; }
    }
    __syncthreads();
    if (t < 32) {
        float ss = 0.f;
#pragma unroll
        for (int w = 0; w < 8; ++w) ss += lsum[w * 32 + t];
        linv[t] = 1.0f / ss;
    }
    __syncthreads();
#pragma unroll
    for (int p = 0; p < 2; ++p) {
        int u = p * 512 + t;
        int jj = u & 31, dq = u >> 5;
        f32x4 v = *(const f32x4*)(Vf + (size_t)(b * S + j0 + jj) * D + dq * 4);
        float inv = linv[jj];
#pragma unroll
        for (int q = 0; q < 4; ++q)
            vtile[(dq * 4 + q) * 40 + jj] = (bf16_t)(v[q] * inv);
    }
    __syncthreads();
    {
        int d = t >> 2, jg = t & 3;
        bf16x8 row = *(const bf16x8*)&vtile[d * 40 + jg * 8];
        size_t j32g = (size_t)b * 64 + jt;
        size_t a = ((j32g * 8 + (d >> 4)) * 64 + jg * 16 + (d & 15)) * 8;
        *(bf16x8*)(Vt2 + a) = row;
    }
}

// ---------------- K3: out = exp2(c*QK^T) @ Vdiv ---------------------------
// 256 blocks = 8b x 16it(128 i) x 2jh(1024 j); 8 waves = 8 i-frags of 16.
// 32 steps x 32 j; K+V dbuf-staged (1 gload_lds/thread each); 42 KiB LDS
// -> 3 blocks/CU; exactly 2 atomicAdd contributions/elem (deterministic).
__global__ __launch_bounds__(512, 4) void k_out(const bf16_t* Qf, const bf16_t* Kf,
                                                const bf16_t* Vt2, float* Out) {
    int l = blockIdx.x;            // 256 blocks
    int b = l & 7, it = (l >> 3) & 15, jh = l >> 7;
    int ibase = it * 128;
    int t = threadIdx.x;
    int lane = t & 63, wid = t >> 6;
    int lr = lane & 15, lg = lane >> 4;
    __shared__ __align__(16) bf16_t pool[21504]; // 42 KiB
    bf16_t* klds = pool;                  // 2 x 4096 elems
    bf16_t* vlds = pool + 8192;           // 2 x 4096 elems
    bf16_t* pl = pool + 16384 + wid * 640; // [16 i][stride 40] per wave

    bf16x8 qf[4];
    int iblk = (b * S + ibase + wid * 16) >> 4;
#pragma unroll
    for (int kk = 0; kk < 4; ++kk)
        qf[kk] = *(const bf16x8*)(Qf + ((size_t)(iblk * 4 + kk) * 64 + lane) * 8);

    f32x4 acc[8] = {};
    const bf16_t* kbase = Kf + ((size_t)((b * S + jh * 1024) >> 4)) * 2048 + t * 8;
    const bf16_t* vbase = Vt2 + (size_t)(b * 64 + jh * 32) * 4096 + t * 8;

    auto stageKV = [&](int bufi, int tt) {
        __builtin_amdgcn_global_load_lds((gu32_t*)(kbase + (size_t)tt * 4096),
                                         (lu32_t*)&klds[bufi * 4096 + t * 8], 16, 0, 0);
        __builtin_amdgcn_global_load_lds((gu32_t*)(vbase + (size_t)tt * 4096),
                                         (lu32_t*)&vlds[bufi * 4096 + t * 8], 16, 0, 0);
    };
    stageKV(0, 0);
    __syncthreads();

    for (int tt = 0; tt < 32; ++tt) {
        int buf = tt & 1;
        if (tt < 31) stageKV(buf ^ 1, tt + 1);
#pragma unroll
        for (int jF = 0; jF < 2; ++jF) {
            const bf16_t* kl = &klds[buf * 4096 + jF * 2048 + lane * 8];
            // swapped QK^T: lane holds S^T[j = jF*16 + lg*4 + r][i = lr]
            f32x4 s = {};
            s = MFMA(*(const bf16x8*)(kl), qf[0], s);
            s = MFMA(*(const bf16x8*)(kl + 512), qf[1], s);
            s = MFMA(*(const bf16x8*)(kl + 1024), qf[2], s);
            s = MFMA(*(const bf16x8*)(kl + 1536), qf[3], s);
            bf16x4 pv;
#pragma unroll
            for (int r = 0; r < 4; ++r) pv[r] = (bf16_t)exp2f(s[r] * C2);
            *(bf16x4*)&pl[lr * 40 + jF * 16 + lg * 4] = pv;
        }
        bf16x8 pa = *(const bf16x8*)&pl[lr * 40 + lg * 8];
        const bf16_t* vl = &vlds[buf * 4096 + lane * 8];
        __builtin_amdgcn_s_setprio(1);
#pragma unroll
        for (int dc = 0; dc < 8; ++dc)
            acc[dc] = MFMA(pa, *(const bf16x8*)(vl + dc * 512), acc[dc]);
        __builtin_amdgcn_s_setprio(0);
        __syncthreads();
    }

#pragma unroll
    for (int dc = 0; dc < 8; ++dc)
#pragma unroll
        for (int r = 0; r < 4; ++r)
            atomicAdd(&Out[(size_t)(b * S + ibase + wid * 16 + lg * 4 + r) * 128 + dc * 16 + lr],
                      acc[dc][r]);
}

extern "C" void kernel_launch(void* const* d_in, const int* in_sizes, int n_in,
                              void* d_out, int out_size, void* d_ws, size_t ws_size,
                              hipStream_t stream) {
    const float* X  = (const float*)d_in[0];
    const float* Wq = (const float*)d_in[1];
    const float* Wk = (const float*)d_in[2];
    const float* Wv = (const float*)d_in[3];
    char* ws = (char*)d_ws;
    bf16_t* Wf  = (bf16_t*)(ws);                 // 768 KiB (frag-major)
    bf16_t* Qf  = (bf16_t*)(ws + (1ull << 20));  // 4 MiB (frag-major)
    bf16_t* Kf  = (bf16_t*)(ws + (5ull << 20));  // 4 MiB (frag-major)
    float*  Vf  = (float*)(ws + (9ull << 20));   // 8 MiB (row-major fp32)
    bf16_t* Vt2 = (bf16_t*)(ws + (17ull << 20)); // 4 MiB (frag-major)
    float* Out = (float*)d_out;

    k_wt<<<dim3(64, 3), dim3(256), 0, stream>>>(Wq, Wk, Wv, Wf);
    k_qkv<<<dim3(256), dim3(512), 0, stream>>>(X, Wf, Qf, Kf, Vf, Out);
    k_sum<<<dim3(512), dim3(512), 0, stream>>>(Qf, Kf, Vf, Vt2);
    k_out<<<dim3(256), dim3(512), 0, stream>>>(Qf, Kf, Vt2, Out);
}

// Round 11
// 87.140 us; speedup vs baseline: 1.0796x; 1.0796x over previous
//
#include <hip/hip_runtime.h>
#include <hip/hip_bf16.h>

typedef __bf16 bf16_t;
typedef bf16_t bf16x4 __attribute__((ext_vector_type(4)));
typedef bf16_t bf16x8 __attribute__((ext_vector_type(8)));
typedef float f32x4 __attribute__((ext_vector_type(4)));
typedef __attribute__((address_space(1))) const unsigned int gu32_t;
typedef __attribute__((address_space(3))) unsigned int lu32_t;

#define MFMA(a, b, c) __builtin_amdgcn_mfma_f32_16x16x32_bf16(a, b, c, 0, 0, 0)

constexpr int B = 8, S = 2048, C = 1024, D = 128;
constexpr float C2 = 0.12751744f; // log2(e)/sqrt(128)

// Frag-major: frag(blk16, kk) = 1KB block; lane = ((k>>3)&3)*16 + (dim&15),
// 8 contiguous k per lane. Serves both A- and B-operands of mfma_16x16x32.

// ---------------- K0: W[c][n] -> Wf frag-major ----------------------------
__global__ __launch_bounds__(256) void k_wt(const float* Wq, const float* Wk, const float* Wv, bf16_t* Wf) {
    int ct = blockIdx.x, w = blockIdx.y; // ct 0..63, w 0..2
    const float* src = (w == 0) ? Wq : ((w == 1) ? Wk : Wv);
    __shared__ bf16_t tile[16][132];
    int t = threadIdx.x;
    int cr = t >> 4, dq = t & 15;
    const float* p = src + (size_t)(ct * 16 + cr) * D + dq * 8;
    f32x4 v0 = *(const f32x4*)p;
    f32x4 v1 = *(const f32x4*)(p + 4);
#pragma unroll
    for (int q = 0; q < 4; ++q) { tile[cr][dq * 8 + q] = (bf16_t)v0[q]; tile[cr][dq * 8 + 4 + q] = (bf16_t)v1[q]; }
    __syncthreads();
    int n = t >> 1, g = t & 1;
    bf16x8 o;
#pragma unroll
    for (int cc = 0; cc < 8; ++cc) o[cc] = tile[g * 8 + cc][n];
    int c8 = ct * 2 + g;
    int nblk = w * 8 + (n >> 4);
    size_t a = ((size_t)(nblk * 32 + (c8 >> 2)) * 64 + (c8 & 3) * 16 + (n & 15)) * 8;
    *(bf16x8*)(Wf + a) = o;
}

// ---------------- K1: fused QKV projection, 256 blocks x 64 rows ----------
// X staged frag-major (2 halves); W register-double-buffered from L2;
// epilogue via LDS bounce -> fully coalesced frag-major stores.
__global__ __launch_bounds__(512, 4) void k_qkv(const float* X, const bf16_t* Wf,
                                                bf16_t* Qf, bf16_t* Kf, float* Vf,
                                                float* Out) {
    __shared__ __align__(16) char pool_[67072]; // 65.5 KiB union
    bf16_t* xfr = (bf16_t*)pool_;               // main loop: 64 frags x 1KB
    bf16_t* qkL = (bf16_t*)pool_;               // epi: [64 m][264] bf16 (Q|K)
    float*  vL  = (float*)(pool_ + 33792);      // epi: [64 m][132] f32
    int mt = blockIdx.x; // 0..255
    int t = threadIdx.x;
    int lane = t & 63, wid = t >> 6;
    int lr = lane & 15, lg = lane >> 4;
    int rw = mt * 64;

    { // zero Out (k_out atomicAdds later): 256*512*4 f32x4 = 8 MiB
        f32x4* O4 = (f32x4*)Out;
        f32x4 z = {};
        int u = mt * 512 + t;
        O4[u] = z; O4[u + 131072] = z; O4[u + 262144] = z; O4[u + 393216] = z;
    }

    auto stage = [&](int h) {
#pragma unroll
        for (int pp = 0; pp < 2; ++pp) {
            f32x4 xa[4], xb[4];
#pragma unroll
            for (int p = 0; p < 4; ++p) {
                int fi = (pp * 4 + p) * 8 + wid;   // rb = fi>>4, kc = fi&15
                int m = rw + (fi >> 4) * 16 + lr;
                int c = h * 512 + (fi & 15) * 32 + lg * 8;
                const float* px = X + (size_t)m * C + c;
                xa[p] = *(const f32x4*)px;
                xb[p] = *(const f32x4*)(px + 4);
            }
#pragma unroll
            for (int p = 0; p < 4; ++p) {
                bf16x8 o;
#pragma unroll
                for (int q = 0; q < 4; ++q) { o[q] = (bf16_t)xa[p][q]; o[4 + q] = (bf16_t)xb[p][q]; }
                *(bf16x8*)&xfr[(size_t)((pp * 4 + p) * 8 + wid) * 512 + lane * 8] = o;
            }
        }
    };

    f32x4 acc[4][3] = {};
    const bf16_t* wbase = Wf + (size_t)(wid * 3) * 32 * 512 + lane * 8;
    auto wld = [&](int nf, int kkg) {
        return *(const bf16x8*)(wbase + (size_t)(nf * 32 + kkg) * 512);
    };

    stage(0);
    bf16x8 wb0[3], wb1[3];
#pragma unroll
    for (int nf = 0; nf < 3; ++nf) wb0[nf] = wld(nf, 0);
    __syncthreads();

#pragma unroll
    for (int h = 0; h < 2; ++h) {
        if (h) { __syncthreads(); stage(1); __syncthreads(); }
#pragma unroll
        for (int kk = 0; kk < 16; ++kk) {
            int kkg = h * 16 + kk;
            bool even = ((kkg & 1) == 0);
            if (kkg < 31) { // prefetch next step's W frags
#pragma unroll
                for (int nf = 0; nf < 3; ++nf) {
                    if (even) wb1[nf] = wld(nf, kkg + 1);
                    else      wb0[nf] = wld(nf, kkg + 1);
                }
            }
#pragma unroll
            for (int rF = 0; rF < 4; ++rF) {
                bf16x8 a = *(const bf16x8*)&xfr[(size_t)(rF * 16 + kk) * 512 + lane * 8];
                if (even) {
                    acc[rF][0] = MFMA(a, wb0[0], acc[rF][0]);
                    acc[rF][1] = MFMA(a, wb0[1], acc[rF][1]);
                    acc[rF][2] = MFMA(a, wb0[2], acc[rF][2]);
                } else {
                    acc[rF][0] = MFMA(a, wb1[0], acc[rF][0]);
                    acc[rF][1] = MFMA(a, wb1[1], acc[rF][1]);
                    acc[rF][2] = MFMA(a, wb1[2], acc[rF][2]);
                }
            }
        }
    }

    // ---- epilogue phase 1: acc -> padded LDS image ----
    __syncthreads(); // xfr reads done; reuse LDS
#pragma unroll
    for (int rF = 0; rF < 4; ++rF)
#pragma unroll
        for (int nf = 0; nf < 3; ++nf) {
            int n = wid * 48 + nf * 16 + lr;
            int sel = (wid * 48 + nf * 16) >> 7; // wave-uniform per nf
#pragma unroll
            for (int r = 0; r < 4; ++r) {
                int mloc = rF * 16 + lg * 4 + r;
                float v = acc[rF][nf][r];
                if (sel == 2) vL[mloc * 132 + (n - 256)] = v;
                else          qkL[mloc * 264 + n] = (bf16_t)v;
            }
        }
    __syncthreads();
    // ---- epilogue phase 2a: Q/K frag-major coalesced stores (32 frags) ----
#pragma unroll
    for (int p = 0; p < 4; ++p) {
        int F = wid * 4 + p; // 0..31
        int isK = F >> 4, iblk = F & 3, dblk = (F >> 2) & 3;
        int m16 = lane & 15, kg = lane >> 4;
        int col = isK * 128 + dblk * 32 + kg * 8;
        bf16x8 o = *(const bf16x8*)&qkL[(iblk * 16 + m16) * 264 + col];
        bf16_t* dst = isK ? Kf : Qf;
        size_t frg = (size_t)((rw >> 4) + iblk) * 4 + dblk;
        *(bf16x8*)(dst + (frg * 64 + lane) * 8) = o;
    }
    // ---- epilogue phase 2b: V row-major coalesced stores ----
#pragma unroll
    for (int p = 0; p < 4; ++p) {
        int u = p * 512 + t;          // 0..2047
        int m = u >> 5, dq = u & 31;
        f32x4 v = *(const f32x4*)&vL[m * 132 + dq * 4];
        *(f32x4*)(Vf + (size_t)(rw + m) * D + dq * 4) = v;
    }
}

// ---------------- K2: column sums l[j] (32 j/block), barrier-free sweep ----
__global__ __launch_bounds__(512, 4) void k_sum(const bf16_t* Qf, const bf16_t* Kf,
                                                const float* Vf, bf16_t* Vt2) {
    int l = blockIdx.x;          // 512 blocks
    int b = l & 7, jt = l >> 3;  // b pinned to XCD; jt 0..63
    int j0 = jt * 32;
    int t = threadIdx.x;
    int lane = t & 63, wid = t >> 6;
    __shared__ __align__(16) bf16_t vtile[128 * 40]; // 10 KiB
    __shared__ float lsum[256];
    __shared__ float linv[32];

    bf16x8 kf[2][4];
    int jblkg = (b * S + j0) >> 4;
#pragma unroll
    for (int jF = 0; jF < 2; ++jF)
#pragma unroll
        for (int kk = 0; kk < 4; ++kk)
            kf[jF][kk] = *(const bf16x8*)(Kf + ((size_t)((jblkg + jF) * 4 + kk) * 64 + lane) * 8);

    float ls0 = 0.f, ls1 = 0.f;
#pragma unroll 4
    for (int tt = 0; tt < 16; ++tt) {
        int iblk = (b * S + wid * 256 + tt * 16) >> 4;
        bf16x8 qa[4];
#pragma unroll
        for (int kk = 0; kk < 4; ++kk)
            qa[kk] = *(const bf16x8*)(Qf + ((size_t)(iblk * 4 + kk) * 64 + lane) * 8);
        f32x4 s0 = {}, s1 = {};
#pragma unroll
        for (int kk = 0; kk < 4; ++kk) {
            s0 = MFMA(qa[kk], kf[0][kk], s0);
            s1 = MFMA(qa[kk], kf[1][kk], s1);
        }
#pragma unroll
        for (int r = 0; r < 4; ++r) { ls0 += exp2f(s0[r] * C2); ls1 += exp2f(s1[r] * C2); }
    }
    {
        float v0 = ls0 + __shfl_xor(ls0, 16); v0 += __shfl_xor(v0, 32);
        float v1 = ls1 + __shfl_xor(ls1, 16); v1 += __shfl_xor(v1, 32);
        if (lane < 16) { lsum[wid * 32 + lane] = v0; lsum[wid * 32 + 16 + lane] = v1; }
    }
    __syncthreads();
    if (t < 32) {
        float ss = 0.f;
#pragma unroll
        for (int w = 0; w < 8; ++w) ss += lsum[w * 32 + t];
        linv[t] = 1.0f / ss;
    }
    __syncthreads();
#pragma unroll
    for (int p = 0; p < 2; ++p) {
        int u = p * 512 + t;
        int jj = u & 31, dq = u >> 5;
        f32x4 v = *(const f32x4*)(Vf + (size_t)(b * S + j0 + jj) * D + dq * 4);
        float inv = linv[jj];
#pragma unroll
        for (int q = 0; q < 4; ++q)
            vtile[(dq * 4 + q) * 40 + jj] = (bf16_t)(v[q] * inv);
    }
    __syncthreads();
    {
        int d = t >> 2, jg = t & 3;
        bf16x8 row = *(const bf16x8*)&vtile[d * 40 + jg * 8];
        size_t j32g = (size_t)b * 64 + jt;
        size_t a = ((j32g * 8 + (d >> 4)) * 64 + jg * 16 + (d & 15)) * 8;
        *(bf16x8*)(Vt2 + a) = row;
    }
}

// ---------------- K3: out = exp2(c*QK^T) @ Vdiv (round-7 structure) -------
// 512 blocks = 8 b x 32 it(64 i) x 2 jh; 8 waves = 4 ig(16 i) x 2 jq(32 j/step).
__global__ __launch_bounds__(512, 4) void k_out(const bf16_t* Qf, const bf16_t* Kf,
                                                const bf16_t* Vt2, float* Out) {
    int l = blockIdx.x;            // 512 blocks
    int b = l & 7, it = (l >> 3) & 31, jh = l >> 8;
    int ibase = it * 64;
    int t = threadIdx.x;
    int lane = t & 63, wid = t >> 6;
    int lr = lane & 15, lg = lane >> 4;
    int ig = wid >> 1, jq = wid & 1;
    __shared__ __align__(16) bf16_t pool[37888]; // 74 KiB
    bf16_t* klds = pool;                          // 2 x 8192 elems
    bf16_t* vlds = pool + 16384;                  // 2 x 8192 elems
    bf16_t* pl = pool + 32768 + wid * 640;        // [16 i][stride 40] per wave

    bf16x8 qf[4];
    int iblk = (b * S + ibase + ig * 16) >> 4;
#pragma unroll
    for (int kk = 0; kk < 4; ++kk)
        qf[kk] = *(const bf16x8*)(Qf + ((size_t)(iblk * 4 + kk) * 64 + lane) * 8);

    f32x4 acc[8] = {};
    const bf16_t* kbase = Kf + (size_t)(b * S + jh * 1024) * 128 + wid * 1024 + lane * 8;
    const bf16_t* vbase = Vt2 + (size_t)(b * 64 + jh * 32) * 4096 + wid * 1024 + lane * 8;

    auto stageKV = [&](int bufi, int tt) {
        const bf16_t* gk = kbase + (size_t)tt * 8192;
        __builtin_amdgcn_global_load_lds((gu32_t*)gk, (lu32_t*)&klds[bufi * 8192 + wid * 1024], 16, 0, 0);
        __builtin_amdgcn_global_load_lds((gu32_t*)(gk + 512), (lu32_t*)&klds[bufi * 8192 + wid * 1024 + 512], 16, 0, 0);
        const bf16_t* gv = vbase + (size_t)tt * 8192;
        __builtin_amdgcn_global_load_lds((gu32_t*)gv, (lu32_t*)&vlds[bufi * 8192 + wid * 1024], 16, 0, 0);
        __builtin_amdgcn_global_load_lds((gu32_t*)(gv + 512), (lu32_t*)&vlds[bufi * 8192 + wid * 1024 + 512], 16, 0, 0);
    };
    stageKV(0, 0);
    __syncthreads();

    for (int tt = 0; tt < 16; ++tt) {
        int buf = tt & 1;
        if (tt < 15) stageKV(buf ^ 1, tt + 1);
#pragma unroll
        for (int jF = 0; jF < 2; ++jF) {
            const bf16_t* kl = &klds[buf * 8192 + ((jq * 2 + jF) * 4) * 512 + lane * 8];
            // swapped QK^T: lane holds S^T[j = (jq*2+jF)*16 + lg*4+r][i = lr]
            f32x4 s = {};
            s = MFMA(*(const bf16x8*)(kl), qf[0], s);
            s = MFMA(*(const bf16x8*)(kl + 512), qf[1], s);
            s = MFMA(*(const bf16x8*)(kl + 1024), qf[2], s);
            s = MFMA(*(const bf16x8*)(kl + 1536), qf[3], s);
            bf16x4 pv;
#pragma unroll
            for (int r = 0; r < 4; ++r) pv[r] = (bf16_t)exp2f(s[r] * C2);
            *(bf16x4*)&pl[lr * 40 + jF * 16 + lg * 4] = pv;
        }
        bf16x8 pa = *(const bf16x8*)&pl[lr * 40 + lg * 8];
        const bf16_t* vl = &vlds[buf * 8192 + jq * 4096 + lane * 8];
        __builtin_amdgcn_s_setprio(1);
#pragma unroll
        for (int dc = 0; dc < 8; ++dc)
            acc[dc] = MFMA(pa, *(const bf16x8*)(vl + dc * 512), acc[dc]);
        __builtin_amdgcn_s_setprio(0);
        __syncthreads();
    }

    float* R = (float*)pool + ig * 2048; // 4 regions x 8 KiB, alias klds (dead)
    if (jq == 1) {
#pragma unroll
        for (int dc = 0; dc < 8; ++dc)
#pragma unroll
            for (int r = 0; r < 4; ++r)
                R[(lg * 4 + r) * 128 + dc * 16 + lr] = acc[dc][r];
    }
    __syncthreads();
    if (jq == 0) {
#pragma unroll
        for (int dc = 0; dc < 8; ++dc)
#pragma unroll
            for (int r = 0; r < 4; ++r)
                atomicAdd(&Out[(size_t)(b * S + ibase + ig * 16 + lg * 4 + r) * 128 + dc * 16 + lr],
                          acc[dc][r] + R[(lg * 4 + r) * 128 + dc * 16 + lr]);
    }
}

extern "C" void kernel_launch(void* const* d_in, const int* in_sizes, int n_in,
                              void* d_out, int out_size, void* d_ws, size_t ws_size,
                              hipStream_t stream) {
    const float* X  = (const float*)d_in[0];
    const float* Wq = (const float*)d_in[1];
    const float* Wk = (const float*)d_in[2];
    const float* Wv = (const float*)d_in[3];
    char* ws = (char*)d_ws;
    bf16_t* Wf  = (bf16_t*)(ws);                 // 768 KiB (frag-major)
    bf16_t* Qf  = (bf16_t*)(ws + (1ull << 20));  // 4 MiB (frag-major)
    bf16_t* Kf  = (bf16_t*)(ws + (5ull << 20));  // 4 MiB (frag-major)
    float*  Vf  = (float*)(ws + (9ull << 20));   // 8 MiB (row-major fp32)
    bf16_t* Vt2 = (bf16_t*)(ws + (17ull << 20)); // 4 MiB (frag-major)
    float* Out = (float*)d_out;

    k_wt<<<dim3(64, 3), dim3(256), 0, stream>>>(Wq, Wk, Wv, Wf);
    k_qkv<<<dim3(256), dim3(512), 0, stream>>>(X, Wf, Qf, Kf, Vf, Out);
    k_sum<<<dim3(512), dim3(512), 0, stream>>>(Qf, Kf, Vf, Vt2);
    k_out<<<dim3(512), dim3(512), 0, stream>>>(Qf, Kf, Vt2, Out);
}